// Round 7
// baseline (986.749 us; speedup 1.0000x reference)
//
#include <hip/hip_runtime.h>
#include <cmath>

#define NNODES 60000
#define DDIM   200
#define NCLS   250

constexpr int ROWS = 32;                 // rows/block -> 1875 blocks exact
constexpr int XP   = 208;                // LDS pitch (shorts)
constexpr int BUFS = ROWS * XP;          // 6656 shorts per buffer
constexpr int SH_SHORTS = 3 * BUFS + 32; // X | A | B | spill pad = 20000 shorts (40 KB)

typedef float  f32x4  __attribute__((ext_vector_type(4)));
typedef short  short8 __attribute__((ext_vector_type(8)));

// ---- ws layout: frag-shuffled W. 14 mats x 16 frags x 7 tiles x 512 shorts.
// shuf[(((m*16+f)*7)+t)*512 + L*8 + i] = W_m[f*16 + (L&15)][t*32 + (L>>4)*8 + i]
constexpr int FRAG = 512;                 // shorts per (frag,tile) block (64 lanes x 8)
constexpr int FSTEP = 7 * FRAG;           // 3584: frag stride
constexpr int W_TOTAL_ELEMS = 14 * 16 * 7 * 512;          // 802816
constexpr size_t W_TOTAL_BYTES = (size_t)W_TOTAL_ELEMS * 2; // 1,605,632 B
// mat ids
constexpr int M_P1C0=0, M_P1C1=1, M_P1C2=2, M_P2A=3, M_P2B=4, M_FX=5, M_FH=6,
              M_IX=7, M_IH=8, M_UX=9, M_UH=10, M_OX=11, M_OH=12, M_FC2=13;

__device__ __forceinline__ short f2b(float f) {      // RNE (prepass)
    union { float f; unsigned u; } x; x.f = f;
    unsigned r = (x.u + 0x7FFFu + ((x.u >> 16) & 1u)) >> 16;
    return (short)r;
}
__device__ __forceinline__ unsigned cvtpk(float lo, float hi) {
    unsigned r; asm("v_cvt_pk_bf16_f32 %0, %1, %2" : "=v"(r) : "v"(lo), "v"(hi));
    return r;
}
__device__ __forceinline__ short f2b1(float f) { return (short)(cvtpk(f, f) & 0xffffu); }
__device__ __forceinline__ float b2f(short s) {
    union { unsigned u; float f; } x; x.u = ((unsigned)(unsigned short)s) << 16;
    return x.f;
}
__device__ __forceinline__ float b2f_lo(unsigned u) { return b2f((short)(u & 0xffffu)); }
__device__ __forceinline__ float b2f_hi(unsigned u) { return b2f((short)(u >> 16)); }
__device__ __forceinline__ float sgm(float x)  { return 1.0f / (1.0f + __expf(-x)); }
__device__ __forceinline__ float tanh_fast(float x) { return 1.0f - 2.0f / (__expf(2.0f * x) + 1.0f); }
__device__ __forceinline__ short8 cvt8(float4 f0, float4 f1) {
    union { unsigned u[4]; short8 s; } c;
    c.u[0] = cvtpk(f0.x, f0.y); c.u[1] = cvtpk(f0.z, f0.w);
    c.u[2] = cvtpk(f1.x, f1.y); c.u[3] = cvtpk(f1.z, f1.w);
    return c.s;
}

// ================= weight prepass: fp32 -> frag-shuffled bf16 =================
__global__ void wprep(const float* __restrict__ p1w, const float* __restrict__ p2w,
                      const float* __restrict__ fxw, const float* __restrict__ fhw,
                      const float* __restrict__ ixw, const float* __restrict__ ihw,
                      const float* __restrict__ uxw, const float* __restrict__ uhw,
                      const float* __restrict__ oxw, const float* __restrict__ ohw,
                      const float* __restrict__ fc2w, short* __restrict__ ws)
{
    int i = blockIdx.x * 256 + threadIdx.x;
    if (i >= W_TOTAL_ELEMS) return;
    const int e  = i & 7;
    const int L  = (i >> 3) & 63;
    const int blk = i >> 9;
    const int t  = blk % 7;
    const int fm = blk / 7;
    const int f  = fm & 15;
    const int m  = fm >> 4;
    const int row = f * 16 + (L & 15);
    const int k   = t * 32 + (L >> 4) * 8 + e;

    const float* src; int stride = 200, off = 0, ncols = 200;
    switch (m) {
        case 0:  src = p1w;  stride = 600; off = 0;   break;
        case 1:  src = p1w;  stride = 600; off = 200; break;
        case 2:  src = p1w;  stride = 600; off = 400; break;
        case 3:  src = p2w;  stride = 400; off = 0;   break;
        case 4:  src = p2w;  stride = 400; off = 200; break;
        case 5:  src = fxw;  break;
        case 6:  src = fhw;  break;
        case 7:  src = ixw;  break;
        case 8:  src = ihw;  break;
        case 9:  src = uxw;  break;
        case 10: src = uhw;  break;
        case 11: src = oxw;  break;
        case 12: src = ohw;  break;
        default: src = fc2w; ncols = 250; break;
    }
    float v = 0.0f;
    if (row < ncols && k < 200) v = src[(long)row * stride + off + k];
    ws[i] = f2b(v);
}

// ================= passes =================
// A from LDS, W frag-shuffled from L2. No barriers, no vmcnt drains.
template<int NF>
__device__ __forceinline__ void pass_lds(f32x4 (&acc)[NF], const short* __restrict__ Arow,
                                         const short* __restrict__ wp)
{
    #pragma unroll
    for (int t = 0; t < 7; ++t) {
        const short8 a = *(const short8*)(Arow + t * 32);
        #pragma unroll
        for (int ni = 0; ni < NF; ++ni) {
            const short8 w = *(const short8*)(wp + ni * FSTEP + t * FRAG);
            acc[ni] = __builtin_amdgcn_mfma_f32_16x16x32_bf16(a, w, acc[ni], 0, 0, 0);
        }
    }
}

// dual pass: acc1 += A x W1 and acc2 += A x W2, A = per-lane fp32 global row.
// aptr already includes + lg*8; tile-6 lg>0 loads are dummies (W zero-padded kills them).
__device__ __forceinline__ void pass_dual(f32x4 (&acc1)[7], f32x4 (&acc2)[7],
    const float* __restrict__ aptr, int lg8,
    const short* __restrict__ w1, const short* __restrict__ w2)
{
    #pragma unroll
    for (int t = 0; t < 7; ++t) {
        const int off = (t * 32 + lg8 <= 192) ? t * 32 : 0;
        const float4 f0 = *(const float4*)(aptr + off);
        const float4 f1 = *(const float4*)(aptr + off + 4);
        const short8 a = cvt8(f0, f1);
        #pragma unroll
        for (int ni = 0; ni < 7; ++ni) {
            const short8 wa = *(const short8*)(w1 + ni * FSTEP + t * FRAG);
            acc1[ni] = __builtin_amdgcn_mfma_f32_16x16x32_bf16(a, wa, acc1[ni], 0, 0, 0);
            const short8 wb = *(const short8*)(w2 + ni * FSTEP + t * FRAG);
            acc2[ni] = __builtin_amdgcn_mfma_f32_16x16x32_bf16(a, wb, acc2[ni], 0, 0, 0);
        }
    }
}

__device__ __forceinline__ void stage_x(short* __restrict__ dst, const float* __restrict__ emb,
                                        const int* __restrict__ tok, int row0, int tid)
{
    #pragma unroll
    for (int it = 0; it < 4; ++it) {
        int u = tid + it * 256;
        if (u < 800) {
            int r = u / 25, cu = (u % 25) * 8;
            const float* s = emb + (long)tok[row0 + r] * DDIM + cu;
            float4 f0 = *(const float4*)s, f1 = *(const float4*)(s + 4);
            *(short8*)(dst + r * XP + cu) = cvt8(f0, f1);
        }
    }
}

#define Z7(A)  { _Pragma("unroll") for (int z_=0; z_<7; ++z_) { _Pragma("unroll") for (int q_=0;q_<4;++q_) A[z_][q_] = 0.0f; } }

__global__ __launch_bounds__(256)
void fused_v4(const int* __restrict__ tok,
              const float* __restrict__ chc,
              const float* __restrict__ chh,
              const float* __restrict__ emb,
              const float* __restrict__ p1b_, const float* __restrict__ p2b_,
              const float* __restrict__ ixb, const float* __restrict__ ihb,
              const float* __restrict__ fxb, const float* __restrict__ fhb,
              const float* __restrict__ uxb, const float* __restrict__ uhb,
              const float* __restrict__ oxb, const float* __restrict__ ohb,
              const float* __restrict__ fc2b,
              const short* __restrict__ ws,
              float* __restrict__ out)
{
    __shared__ __align__(16) short SH[SH_SHORTS];
    short* X  = SH;               // x
    short* BA = SH + BUFS;        // control -> h
    short* BB = SH + 2 * BUFS;    // hs

    const int tid  = threadIdx.x;
    const int lane = tid & 63;
    const int wv   = tid >> 6, wm = wv >> 1, wn = wv & 1;
    const int l15  = tid & 15, lg = lane >> 4;
    const int lg8  = lg * 8;
    const int row0 = blockIdx.x * ROWS;
    const int mrow = wm * 16 + l15;           // A-frag local row
    const long grow = row0 + mrow;

    // ---- zero arena, stage x ----
    {
        short8 z = (short8)0;
        short8* shv = (short8*)SH;
        #pragma unroll 1
        for (int i = tid; i < SH_SHORTS / 8; i += 256) shv[i] = z;
    }
    __syncthreads();
    stage_x(X, emb, tok, row0, tid);
    __syncthreads();

    // per-lane pointers
    const short* Xrow = X  + mrow * XP + lg8;
    const short* Arow = BA + mrow * XP + lg8;
    const short* Brow = BB + mrow * XP + lg8;
    const float* chrow = chh + grow * 800 + lg8;

    // frag-shuffled W bases (per wave half + lane)
    #define WP7(m)  (ws + (size_t)((m) * 16 + wn * 7) * FSTEP + lane * 8)
    #define WP8(m)  (ws + (size_t)((m) * 16 + wn * 8) * FSTEP + lane * 8)

    f32x4 g[7];

    // ==== FX: fxr = x @ fx^T + b (bf16-packed) ====
    unsigned fxr[7][2];
    Z7(g);
    pass_lds<7>(g, Xrow, WP7(M_FX));
    #pragma unroll
    for (int ni = 0; ni < 7; ++ni) {
        const int col = wn * 112 + ni * 16 + l15;
        const float b = (col < DDIM) ? fxb[col] : 0.0f;
        fxr[ni][0] = cvtpk(g[ni][0] + b, g[ni][1] + b);
        fxr[ni][1] = cvtpk(g[ni][2] + b, g[ni][3] + b);
    }

    // ==== children 0..2: p1 += ch_c x P1C_c ; fh = ch_c x FH -> csum ====
    f32x4 p1[7];
    Z7(p1);
    float csum[7][4];
    #pragma unroll
    for (int ni = 0; ni < 7; ++ni)
        #pragma unroll
        for (int j = 0; j < 4; ++j) csum[ni][j] = 0.0f;

    #pragma unroll 1
    for (int c = 0; c < 3; ++c) {
        f32x4 fh[7];
        Z7(fh);
        pass_dual(p1, fh, chrow + c * 200, lg8,
                  ws + (size_t)(c * 16 + wn * 7) * FSTEP + lane * 8, WP7(M_FH));
        #pragma unroll
        for (int ni = 0; ni < 7; ++ni) {
            const int col = wn * 112 + ni * 16 + l15;
            if (col < DDIM) {
                const float fb = fhb[col];
                #pragma unroll
                for (int j = 0; j < 4; ++j) {
                    const int lr = wm * 16 + lg * 4 + j;
                    const float cv = chc[(long)(row0 + lr) * 800 + c * 200 + col];
                    const unsigned pk = fxr[ni][j >> 1];
                    const float fx = (j & 1) ? b2f_hi(pk) : b2f_lo(pk);
                    csum[ni][j] += sgm(fh[ni][j] + fb + fx) * cv;
                }
            }
        }
    }

    // ---- control = relu(p1 + b) -> BA (no barrier yet; c=3 pass doesn't touch BA) ----
    #pragma unroll
    for (int ni = 0; ni < 7; ++ni) {
        const int col = wn * 112 + ni * 16 + l15;
        if (col < DDIM) {
            const float b = p1b_[col];
            #pragma unroll
            for (int j = 0; j < 4; ++j) {
                const int lr = wm * 16 + lg * 4 + j;
                BA[lr * XP + col] = f2b1(fmaxf(p1[ni][j] + b, 0.0f));
            }
        }
    }

    // ==== child 3: p2 = ch3 x P2B ; fh = ch3 x FH -> csum ====
    f32x4 p2[7];
    Z7(p2);
    {
        f32x4 fh[7];
        Z7(fh);
        pass_dual(p2, fh, chrow + 600, lg8, WP7(M_P2B), WP7(M_FH));
        #pragma unroll
        for (int ni = 0; ni < 7; ++ni) {
            const int col = wn * 112 + ni * 16 + l15;
            if (col < DDIM) {
                const float fb = fhb[col];
                #pragma unroll
                for (int j = 0; j < 4; ++j) {
                    const int lr = wm * 16 + lg * 4 + j;
                    const float cv = chc[(long)(row0 + lr) * 800 + 600 + col];
                    const unsigned pk = fxr[ni][j >> 1];
                    const float fx = (j & 1) ? b2f_hi(pk) : b2f_lo(pk);
                    csum[ni][j] += sgm(fh[ni][j] + fb + fx) * cv;
                }
            }
        }
    }
    __syncthreads();   // control visible

    // ==== P2A: p2 += control x P2A ; hs = relu -> BB ====
    pass_lds<7>(p2, Arow, WP7(M_P2A));
    #pragma unroll
    for (int ni = 0; ni < 7; ++ni) {
        const int col = wn * 112 + ni * 16 + l15;
        if (col < DDIM) {
            const float b = p2b_[col];
            #pragma unroll
            for (int j = 0; j < 4; ++j) {
                const int lr = wm * 16 + lg * 4 + j;
                BB[lr * XP + col] = f2b1(fmaxf(p2[ni][j] + b, 0.0f));
            }
        }
    }
    __syncthreads();   // hs visible

    // ==== I gate ====
    unsigned gi[7][2];
    Z7(g);
    pass_lds<7>(g, Xrow, WP7(M_IX));
    pass_lds<7>(g, Brow, WP7(M_IH));
    #pragma unroll
    for (int ni = 0; ni < 7; ++ni) {
        const int col = wn * 112 + ni * 16 + l15;
        const float b = (col < DDIM) ? (ixb[col] + ihb[col]) : 0.0f;
        gi[ni][0] = cvtpk(sgm(g[ni][0] + b), sgm(g[ni][1] + b));
        gi[ni][1] = cvtpk(sgm(g[ni][2] + b), sgm(g[ni][3] + b));
    }

    // ==== U gate: csum <- i*tanh(u) + csum (= c value) ====
    Z7(g);
    pass_lds<7>(g, Xrow, WP7(M_UX));
    pass_lds<7>(g, Brow, WP7(M_UH));
    #pragma unroll
    for (int ni = 0; ni < 7; ++ni) {
        const int col = wn * 112 + ni * 16 + l15;
        const float b = (col < DDIM) ? (uxb[col] + uhb[col]) : 0.0f;
        #pragma unroll
        for (int j = 0; j < 4; ++j) {
            const unsigned pk = gi[ni][j >> 1];
            const float iv = (j & 1) ? b2f_hi(pk) : b2f_lo(pk);
            csum[ni][j] = iv * tanh_fast(g[ni][j] + b) + csum[ni][j];
        }
    }

    // ==== O gate: h = sgm(o)*tanh(c) -> BA ====
    Z7(g);
    pass_lds<7>(g, Xrow, WP7(M_OX));
    pass_lds<7>(g, Brow, WP7(M_OH));
    #pragma unroll
    for (int ni = 0; ni < 7; ++ni) {
        const int col = wn * 112 + ni * 16 + l15;
        if (col < DDIM) {
            const float b = oxb[col] + ohb[col];
            #pragma unroll
            for (int j = 0; j < 4; ++j) {
                const int lr = wm * 16 + lg * 4 + j;
                BA[lr * XP + col] = f2b1(sgm(g[ni][j] + b) * tanh_fast(csum[ni][j]));
            }
        }
    }
    __syncthreads();   // h visible

    // ==== FC2: logits = h @ fc2^T + b ====
    f32x4 o8[8];
    #pragma unroll
    for (int ni = 0; ni < 8; ++ni)
        #pragma unroll
        for (int q = 0; q < 4; ++q) o8[ni][q] = 0.0f;
    pass_lds<8>(o8, Arow, WP8(M_FC2));
    #pragma unroll
    for (int ni = 0; ni < 8; ++ni) {
        const int col = wn * 128 + ni * 16 + l15;
        if (col < NCLS) {
            const float b = fc2b[col];
            #pragma unroll
            for (int j = 0; j < 4; ++j) {
                const int lr = wm * 16 + lg * 4 + j;
                out[(long)(row0 + lr) * NCLS + col] = o8[ni][j] + b;
            }
        }
    }
    #undef WP7
    #undef WP8
}

// ================= fallback fp32 kernel (used only if ws too small) =================
constexpr int FRT = 32, FBK = 16, FNT = 256, FRTP = FRT + 4, FBUFP = 208;
__device__ __forceinline__ float sgm_f(float x) { return 1.0f / (1.0f + expf(-x)); }

__device__ __forceinline__ void f_stage(
    float (*aT)[FRTP], float (*wt)[FNT], int row0, int k0,
    const float* a1g, int a1pitch, const int* gidx, const float* a1l, int a1lp, int K1,
    const float* a2g, int a2pitch, const float* a2l, int a2lp, int K2,
    const float* wa, int wap, int KW1, const float* wb, int wbp,
    int ncols, int tid)
{
    const int Ktot = K1 + K2;
    {
        const int kk = tid & 15, k = k0 + kk;
        #pragma unroll
        for (int h = 0; h < 2; ++h) {
            const int r = (tid >> 4) + h * 16;
            float v = 0.0f;
            if (k < K1) {
                if (a1l) v = a1l[r * a1lp + k];
                else {
                    const long rb = gidx ? (long)gidx[row0 + r] * a1pitch : (long)(row0 + r) * a1pitch;
                    v = a1g[rb + k];
                }
            } else if (k < Ktot) {
                if (a2l) v = a2l[r * a2lp + (k - K1)];
                else     v = a2g[(long)(row0 + r) * a2pitch + (k - K1)];
            }
            aT[kk][r] = v;
        }
    }
    {
        const int col = tid;
        #pragma unroll
        for (int kk = 0; kk < FBK; ++kk) {
            const int k = k0 + kk; float v = 0.0f;
            if (col < ncols && k < Ktot) {
                if (k < KW1) v = wa[(long)col * wap + k];
                else         v = wb[(long)col * wbp + (k - KW1)];
            }
            wt[kk][col] = v;
        }
    }
}
__device__ __forceinline__ void f_gemm(
    float (*aT)[FRTP], float (*wt)[FNT], float acc[8][4], int row0,
    const float* a1g, int a1p, const int* gidx, const float* a1l, int a1lp, int K1,
    const float* a2g, int a2p, const float* a2l, int a2lp, int K2,
    const float* wa, int wap, int KW1, const float* wb, int wbp,
    int ncols, int tid, int tr, int tc)
{
    #pragma unroll
    for (int j = 0; j < 8; ++j)
        #pragma unroll
        for (int i = 0; i < 4; ++i) acc[j][i] = 0.0f;
    const int Ktot = K1 + K2;
    for (int k0 = 0; k0 < Ktot; k0 += FBK) {
        __syncthreads();
        f_stage(aT, wt, row0, k0, a1g, a1p, gidx, a1l, a1lp, K1, a2g, a2p, a2l, a2lp, K2,
                wa, wap, KW1, wb, wbp, ncols, tid);
        __syncthreads();
        #pragma unroll
        for (int kk = 0; kk < FBK; ++kk) {
            const float w0 = wt[kk][tc*4+0], w1 = wt[kk][tc*4+1], w2 = wt[kk][tc*4+2], w3 = wt[kk][tc*4+3];
            #pragma unroll
            for (int j = 0; j < 8; ++j) {
                const float a = aT[kk][tr*8+j];
                acc[j][0] = fmaf(a, w0, acc[j][0]); acc[j][1] = fmaf(a, w1, acc[j][1]);
                acc[j][2] = fmaf(a, w2, acc[j][2]); acc[j][3] = fmaf(a, w3, acc[j][3]);
            }
        }
    }
}
__global__ __launch_bounds__(256)
void fused_fp32(const int* tok, const float* chc, const float* chh, const float* emb,
                const float* p1w, const float* p1b, const float* p2w, const float* p2b,
                const float* ixw, const float* ixb, const float* ihw, const float* ihb,
                const float* fxw, const float* fxb, const float* fhw, const float* fhb,
                const float* uxw, const float* uxb, const float* uhw, const float* uhb,
                const float* oxw, const float* oxb, const float* ohw, const float* ohb,
                const float* fc2w, const float* fc2b, float* out)
{
    __shared__ float aT[FBK][FRTP]; __shared__ float wt[FBK][FNT]; __shared__ float buf[FRT][FBUFP];
    const int tid = threadIdx.x, tr = tid >> 6, tc = tid & 63, c0 = tc * 4;
    const int row0 = blockIdx.x * FRT;
    float acc[8][4];
    f_gemm(aT, wt, acc, row0, chh, 800, nullptr, nullptr, 0, 600, nullptr,0,nullptr,0,0, p1w,600,600,nullptr,0, DDIM, tid,tr,tc);
    if (c0 < DDIM) { const float4 b = *(const float4*)&p1b[c0];
        #pragma unroll
        for (int j=0;j<8;++j){int r=tr*8+j; buf[r][c0]=fmaxf(acc[j][0]+b.x,0.f); buf[r][c0+1]=fmaxf(acc[j][1]+b.y,0.f); buf[r][c0+2]=fmaxf(acc[j][2]+b.z,0.f); buf[r][c0+3]=fmaxf(acc[j][3]+b.w,0.f);} }
    f_gemm(aT, wt, acc, row0, nullptr,0,nullptr,&buf[0][0],FBUFP,200, chh+600,800,nullptr,0,200, p2w,400,400,nullptr,0, DDIM, tid,tr,tc);
    if (c0 < DDIM) { const float4 b = *(const float4*)&p2b[c0];
        #pragma unroll
        for (int j=0;j<8;++j){int r=tr*8+j; buf[r][c0]=fmaxf(acc[j][0]+b.x,0.f); buf[r][c0+1]=fmaxf(acc[j][1]+b.y,0.f); buf[r][c0+2]=fmaxf(acc[j][2]+b.z,0.f); buf[r][c0+3]=fmaxf(acc[j][3]+b.w,0.f);} }
    f_gemm(aT, wt, acc, row0, emb, DDIM, tok, nullptr,0,200, nullptr,0,nullptr,0,0, fxw,200,200,nullptr,0, DDIM, tid,tr,tc);
    float fxr[8][4];
    { float4 b = make_float4(0,0,0,0); if (c0<DDIM) b = *(const float4*)&fxb[c0];
      #pragma unroll
      for (int j=0;j<8;++j){fxr[j][0]=acc[j][0]+b.x;fxr[j][1]=acc[j][1]+b.y;fxr[j][2]=acc[j][2]+b.z;fxr[j][3]=acc[j][3]+b.w;} }
    float csum[8][4];
    #pragma unroll
    for (int j=0;j<8;++j)
        #pragma unroll
        for (int i=0;i<4;++i) csum[j][i]=0.f;
    for (int cc_=0; cc_<4; ++cc_) {
        f_gemm(aT, wt, acc, row0, chh+cc_*200,800,nullptr,nullptr,0,200, nullptr,0,nullptr,0,0, fhw,200,200,nullptr,0, DDIM, tid,tr,tc);
        if (c0 < DDIM) { const float4 b = *(const float4*)&fhb[c0];
            #pragma unroll
            for (int j=0;j<8;++j){ const long r=row0+tr*8+j; const float4 cv=*(const float4*)&chc[r*800+cc_*200+c0];
                csum[j][0]+=sgm_f(acc[j][0]+b.x+fxr[j][0])*cv.x; csum[j][1]+=sgm_f(acc[j][1]+b.y+fxr[j][1])*cv.y;
                csum[j][2]+=sgm_f(acc[j][2]+b.z+fxr[j][2])*cv.z; csum[j][3]+=sgm_f(acc[j][3]+b.w+fxr[j][3])*cv.w; } }
    }
    f_gemm(aT, wt, acc, row0, emb, DDIM, tok, nullptr,0,200, nullptr,0,&buf[0][0],FBUFP,200, ixw,200,200,ihw,200, DDIM, tid,tr,tc);
    float gi[8][4];
    { float4 b1=make_float4(0,0,0,0),b2=b1; if(c0<DDIM){b1=*(const float4*)&ixb[c0];b2=*(const float4*)&ihb[c0];}
      #pragma unroll
      for(int j=0;j<8;++j){gi[j][0]=sgm_f(acc[j][0]+b1.x+b2.x);gi[j][1]=sgm_f(acc[j][1]+b1.y+b2.y);gi[j][2]=sgm_f(acc[j][2]+b1.z+b2.z);gi[j][3]=sgm_f(acc[j][3]+b1.w+b2.w);} }
    f_gemm(aT, wt, acc, row0, emb, DDIM, tok, nullptr,0,200, nullptr,0,&buf[0][0],FBUFP,200, uxw,200,200,uhw,200, DDIM, tid,tr,tc);
    float cval[8][4];
    { float4 b1=make_float4(0,0,0,0),b2=b1; if(c0<DDIM){b1=*(const float4*)&uxb[c0];b2=*(const float4*)&uhb[c0];}
      #pragma unroll
      for(int j=0;j<8;++j){cval[j][0]=gi[j][0]*tanhf(acc[j][0]+b1.x+b2.x)+csum[j][0];cval[j][1]=gi[j][1]*tanhf(acc[j][1]+b1.y+b2.y)+csum[j][1];
                           cval[j][2]=gi[j][2]*tanhf(acc[j][2]+b1.z+b2.z)+csum[j][2];cval[j][3]=gi[j][3]*tanhf(acc[j][3]+b1.w+b2.w)+csum[j][3];} }
    f_gemm(aT, wt, acc, row0, emb, DDIM, tok, nullptr,0,200, nullptr,0,&buf[0][0],FBUFP,200, oxw,200,200,ohw,200, DDIM, tid,tr,tc);
    if (c0 < DDIM) { const float4 b1=*(const float4*)&oxb[c0], b2=*(const float4*)&ohb[c0];
        #pragma unroll
        for(int j=0;j<8;++j){int r=tr*8+j;
            buf[r][c0]=sgm_f(acc[j][0]+b1.x+b2.x)*tanhf(cval[j][0]); buf[r][c0+1]=sgm_f(acc[j][1]+b1.y+b2.y)*tanhf(cval[j][1]);
            buf[r][c0+2]=sgm_f(acc[j][2]+b1.z+b2.z)*tanhf(cval[j][2]); buf[r][c0+3]=sgm_f(acc[j][3]+b1.w+b2.w)*tanhf(cval[j][3]);} }
    f_gemm(aT, wt, acc, row0, nullptr,0,nullptr,&buf[0][0],FBUFP,200, nullptr,0,nullptr,0,0, fc2w,200,200,nullptr,0, NCLS, tid,tr,tc);
    #pragma unroll
    for (int j=0;j<8;++j){ const long r=row0+tr*8+j;
        #pragma unroll
        for (int i=0;i<4;++i){ const int col=c0+i; if (col<NCLS) out[r*NCLS+col]=acc[j][i]+fc2b[col]; } }
}

// ================= launch =================
extern "C" void kernel_launch(void* const* d_in, const int* in_sizes, int n_in,
                              void* d_out, int out_size, void* d_ws, size_t ws_size,
                              hipStream_t stream)
{
    const int*   tok  = (const int*)  d_in[0];
    const float* chc  = (const float*)d_in[1];
    const float* chh  = (const float*)d_in[2];
    const float* emb  = (const float*)d_in[3];
    const float* p1w  = (const float*)d_in[4];
    const float* p1b  = (const float*)d_in[5];
    const float* p2w  = (const float*)d_in[6];
    const float* p2b  = (const float*)d_in[7];
    const float* ixw  = (const float*)d_in[8];
    const float* ixb  = (const float*)d_in[9];
    const float* ihw  = (const float*)d_in[10];
    const float* ihb  = (const float*)d_in[11];
    const float* fxw  = (const float*)d_in[12];
    const float* fxb  = (const float*)d_in[13];
    const float* fhw  = (const float*)d_in[14];
    const float* fhb  = (const float*)d_in[15];
    const float* uxw  = (const float*)d_in[16];
    const float* uxb  = (const float*)d_in[17];
    const float* uhw  = (const float*)d_in[18];
    const float* uhb  = (const float*)d_in[19];
    const float* oxw  = (const float*)d_in[20];
    const float* oxb  = (const float*)d_in[21];
    const float* ohw  = (const float*)d_in[22];
    const float* ohb  = (const float*)d_in[23];
    const float* fc2w = (const float*)d_in[24];
    const float* fc2b = (const float*)d_in[25];
    float* out = (float*)d_out;

    if (ws_size >= W_TOTAL_BYTES) {
        short* ws = (short*)d_ws;
        hipLaunchKernelGGL(wprep, dim3((W_TOTAL_ELEMS + 255) / 256), dim3(256), 0, stream,
                           p1w, p2w, fxw, fhw, ixw, ihw, uxw, uhw, oxw, ohw, fc2w, ws);
        hipLaunchKernelGGL(fused_v4, dim3(NNODES / ROWS), dim3(256), 0, stream,
                           tok, chc, chh, emb,
                           p1b, p2b, ixb, ihb, fxb, fhb, uxb, uhb, oxb, ohb, fc2b,
                           ws, out);
    } else {
        hipLaunchKernelGGL(fused_fp32, dim3(NNODES / FRT), dim3(256), 0, stream,
                           tok, chc, chh, emb, p1w, p1b, p2w, p2b,
                           ixw, ixb, ihw, ihb, fxw, fxb, fhw, fhb,
                           uxw, uxb, uhw, uhb, oxw, oxb, ohw, ohb, fc2w, fc2b, out);
    }
}

// Round 9
// 627.030 us; speedup vs baseline: 1.5737x; 1.5737x over previous
//
#include <hip/hip_runtime.h>
#include <cmath>

#define NNODES 60000
#define DDIM   200
#define NCLS   250

constexpr int ROWS = 64;                 // rows/block -> 938 blocks (last block 32-row tail)
constexpr int XP   = 232;                // act pitch (shorts): 464B -> ~2-way banks
constexpr int ABUF = 64 * 32;            // A tile floats (8KB)

typedef float  f32x4  __attribute__((ext_vector_type(4)));
typedef short  short8 __attribute__((ext_vector_type(8)));

// ---- ws layout (R7-verified): 14 mats x 16 frags x 7 tiles x 512 shorts.
// ws[(((m*16+f)*7)+t)*512 + L*8 + e] = W_m[f*16 + (L&15)][t*32 + (L>>4)*8 + e]
constexpr int FRAG  = 512;
constexpr int FSTEP = 7 * FRAG;          // 3584
constexpr int W_TOTAL_ELEMS = 14 * 16 * 7 * 512;            // 802816
constexpr size_t W_TOTAL_BYTES = (size_t)W_TOTAL_ELEMS * 2; // 1,605,632 B
constexpr int M_P1C0=0, M_P1C1=1, M_P1C2=2, M_P2A=3, M_P2B=4, M_FX=5, M_FH=6,
              M_IX=7, M_IH=8, M_UX=9, M_UH=10, M_OX=11, M_OH=12, M_FC2=13;

#define WAITV0() asm volatile("s_waitcnt vmcnt(0)" ::: "memory")
#define BARR()   asm volatile("s_barrier" ::: "memory")

__device__ __forceinline__ short f2b(float f) {      // RNE (prepass)
    union { float f; unsigned u; } x; x.f = f;
    unsigned r = (x.u + 0x7FFFu + ((x.u >> 16) & 1u)) >> 16;
    return (short)r;
}
__device__ __forceinline__ unsigned cvtpk(float lo, float hi) {
    unsigned r; asm("v_cvt_pk_bf16_f32 %0, %1, %2" : "=v"(r) : "v"(lo), "v"(hi));
    return r;
}
__device__ __forceinline__ short f2b1(float f) { return (short)(cvtpk(f, f) & 0xffffu); }
__device__ __forceinline__ float b2f(short s) {
    union { unsigned u; float f; } x; x.u = ((unsigned)(unsigned short)s) << 16;
    return x.f;
}
__device__ __forceinline__ float b2f_lo(unsigned u) { return b2f((short)(u & 0xffffu)); }
__device__ __forceinline__ float b2f_hi(unsigned u) { return b2f((short)(u >> 16)); }
__device__ __forceinline__ float sgm(float x)  { return 1.0f / (1.0f + __expf(-x)); }
__device__ __forceinline__ float tanh_fast(float x) { return 1.0f - 2.0f / (__expf(2.0f * x) + 1.0f); }
__device__ __forceinline__ short8 cvt8(float4 f0, float4 f1) {
    union { unsigned u[4]; short8 s; } c;
    c.u[0] = cvtpk(f0.x, f0.y); c.u[1] = cvtpk(f0.z, f0.w);
    c.u[2] = cvtpk(f1.x, f1.y); c.u[3] = cvtpk(f1.z, f1.w);
    return c.s;
}

// ================= weight prepass (verbatim from R7 — verified) =================
__global__ void wprep(const float* __restrict__ p1w, const float* __restrict__ p2w,
                      const float* __restrict__ fxw, const float* __restrict__ fhw,
                      const float* __restrict__ ixw, const float* __restrict__ ihw,
                      const float* __restrict__ uxw, const float* __restrict__ uhw,
                      const float* __restrict__ oxw, const float* __restrict__ ohw,
                      const float* __restrict__ fc2w, short* __restrict__ ws)
{
    int i = blockIdx.x * 256 + threadIdx.x;
    if (i >= W_TOTAL_ELEMS) return;
    const int e  = i & 7;
    const int L  = (i >> 3) & 63;
    const int blk = i >> 9;
    const int t  = blk % 7;
    const int fm = blk / 7;
    const int f  = fm & 15;
    const int m  = fm >> 4;
    const int row = f * 16 + (L & 15);
    const int k   = t * 32 + (L >> 4) * 8 + e;

    const float* src; int stride = 200, off = 0, ncols = 200;
    switch (m) {
        case 0:  src = p1w;  stride = 600; off = 0;   break;
        case 1:  src = p1w;  stride = 600; off = 200; break;
        case 2:  src = p1w;  stride = 600; off = 400; break;
        case 3:  src = p2w;  stride = 400; off = 0;   break;
        case 4:  src = p2w;  stride = 400; off = 200; break;
        case 5:  src = fxw;  break;
        case 6:  src = fhw;  break;
        case 7:  src = ixw;  break;
        case 8:  src = ihw;  break;
        case 9:  src = uxw;  break;
        case 10: src = uhw;  break;
        case 11: src = oxw;  break;
        case 12: src = ohw;  break;
        default: src = fc2w; ncols = 250; break;
    }
    float v = 0.0f;
    if (row < ncols && k < 200) v = src[(long)row * stride + off + k];
    ws[i] = f2b(v);
}

// ================= A staging: fp32 chh -> swizzled LDS via global_load_lds =================
// dest linear db = qq*1024 + lane*16 ; r = db>>7 (0..63), g = (db>>4)&7
// LDS position-chunk g holds logical k-chunk (g ^ (r&7))  [both-sides swizzle, rule #21]
__device__ __forceinline__ void stageA(float* __restrict__ dst,
                                       const float* __restrict__ chh,
                                       long row0, int colofs, int t,
                                       int wv, int lane)
{
    #pragma unroll
    for (int i = 0; i < 2; ++i) {
        const int qq = wv * 2 + i;
        const int r  = qq * 8 + (lane >> 3);
        const int g  = lane & 7;
        int k = t * 32 + ((g ^ (r & 7)) * 4);
        if (colofs + k >= 800) k = 0;            // OOB guard (colofs=600, tile 6)
        long grow = row0 + r; if (grow >= NNODES) grow = NNODES - 1;
        const float* srcp = chh + grow * 800 + colofs + k;
        float* dstp = dst + qq * 256;            // wave-uniform base; HW adds lane*16
        __builtin_amdgcn_global_load_lds((const __attribute__((address_space(1))) unsigned*)srcp,
                                         (__attribute__((address_space(3))) unsigned*)dstp, 16, 0, 0);
    }
}

// ================= GA pass: minimum-2-phase pipeline (wait BEFORE barrier BEFORE read) ====
__device__ __forceinline__ void ga_pass(f32x4 (&acc)[2][7],
    const float* __restrict__ chh, long row0, int colofs,
    const short* __restrict__ wp,     // ws + (m*16 + wn*7)*FSTEP + lane*8
    float* __restrict__ Ab,           // 2 x ABUF floats
    int wv, int lane, int wm, int l15, int lg)
{
    stageA(Ab, chh, row0, colofs, 0, wv, lane);
    WAITV0(); BARR();                 // tile 0 visible to all waves
    #pragma unroll
    for (int t = 0; t < 7; ++t) {
        if (t < 6)                    // issue next tile BEFORE compute (latency hides under it)
            stageA(Ab + ((t + 1) & 1) * ABUF, chh, row0, colofs, t + 1, wv, lane);
        short8 a[2];
        #pragma unroll
        for (int mi = 0; mi < 2; ++mi) {
            const int ar = wm * 32 + mi * 16 + l15;
            const int sw = ar & 7;
            const float* ab = Ab + (t & 1) * ABUF + ar * 32;
            float4 fa = *(const float4*)(ab + (((2 * lg)     ^ sw) * 4));
            float4 fb = *(const float4*)(ab + (((2 * lg + 1) ^ sw) * 4));
            a[mi] = cvt8(fa, fb);
        }
        #pragma unroll
        for (int ni = 0; ni < 7; ++ni) {
            const short8 w = *(const short8*)(wp + ni * FSTEP + t * FRAG);
            acc[0][ni] = __builtin_amdgcn_mfma_f32_16x16x32_bf16(a[0], w, acc[0][ni], 0, 0, 0);
            acc[1][ni] = __builtin_amdgcn_mfma_f32_16x16x32_bf16(a[1], w, acc[1][ni], 0, 0, 0);
        }
        if (t < 6) {
            WAITV0();                 // my t+1 loads retired ...
            BARR();                   // ... and so are everyone's -> buf[(t+1)&1] readable
        }
    }
    BARR();                           // all waves done reading buf0 before next pass re-stages it
}

// ================= LA pass: A from LDS acts (bf16), W per-lane from L2, barrier-free =================
template<int NF>
__device__ __forceinline__ void la_pass(f32x4 (&acc)[2][NF],
    const short* __restrict__ act,    // act base
    const short* __restrict__ wp,
    int wm, int l15, int lg)
{
    const short* a0 = act + (wm * 32 + l15) * XP + lg * 8;
    const short* a1 = a0 + 16 * XP;
    #pragma unroll
    for (int t = 0; t < 7; ++t) {
        const short8 x0 = *(const short8*)(a0 + t * 32);
        const short8 x1 = *(const short8*)(a1 + t * 32);
        #pragma unroll
        for (int ni = 0; ni < NF; ++ni) {
            const short8 w = *(const short8*)(wp + ni * FSTEP + t * FRAG);
            acc[0][ni] = __builtin_amdgcn_mfma_f32_16x16x32_bf16(x0, w, acc[0][ni], 0, 0, 0);
            acc[1][ni] = __builtin_amdgcn_mfma_f32_16x16x32_bf16(x1, w, acc[1][ni], 0, 0, 0);
        }
    }
}

#define Z27(A)  { _Pragma("unroll") for (int m_=0;m_<2;++m_) { _Pragma("unroll") for (int z_=0; z_<7; ++z_) { _Pragma("unroll") for (int q_=0;q_<4;++q_) A[m_][z_][q_] = 0.0f; } } }

__global__ __launch_bounds__(256, 2)
void fused_v6(const int* __restrict__ tok,
              const float* __restrict__ chc,
              const float* __restrict__ chh,
              const float* __restrict__ emb,
              const float* __restrict__ p1b_, const float* __restrict__ p2b_,
              const float* __restrict__ ixb, const float* __restrict__ ihb,
              const float* __restrict__ fxb, const float* __restrict__ fhb,
              const float* __restrict__ uxb, const float* __restrict__ uhb,
              const float* __restrict__ oxb, const float* __restrict__ ohb,
              const float* __restrict__ fc2b,
              const short* __restrict__ ws,
              float* __restrict__ out)
{
    __shared__ __align__(16) short Xb[ROWS * XP];   // x
    __shared__ __align__(16) short Hb[ROWS * XP];   // control -> hs -> h
    __shared__ __align__(16) float Ab[2 * ABUF];    // A dbuf (16KB)

    const int tid  = threadIdx.x;
    const int lane = tid & 63;
    const int wv   = tid >> 6, wm = wv >> 1, wn = wv & 1;
    const int l15  = tid & 15, lg = lane >> 4;
    const long row0 = (long)blockIdx.x * ROWS;

    // ---- zero act pads (cols >=200 read by tile 6), stage x ----
    {
        short8 z = (short8)0;
        #pragma unroll 1
        for (int i = tid; i < (2 * ROWS * XP) / 8; i += 256) ((short8*)Xb)[i] = z;
    }
    __syncthreads();
    {
        #pragma unroll
        for (int it = 0; it < 7; ++it) {
            int u = tid + it * 256;
            if (u < 1600) {
                int r = u / 25, cu = (u % 25) * 8;
                long rg = row0 + r; if (rg >= NNODES) rg = NNODES - 1;
                const float* s = emb + (long)tok[rg] * DDIM + cu;
                float4 f0 = *(const float4*)s, f1 = *(const float4*)(s + 4);
                *(short8*)(Xb + r * XP + cu) = cvt8(f0, f1);
            }
        }
    }
    __syncthreads();

    #define WP7(m)  (ws + (size_t)((m) * 16 + wn * 7) * FSTEP + lane * 8)
    #define WP8(m)  (ws + (size_t)((m) * 16 + wn * 8) * FSTEP + lane * 8)

    f32x4 g[2][7];

    // ==== FX: fxr = x @ fx^T + b (bf16-packed regs) ====
    unsigned fxr[2][7][2];
    Z27(g);
    la_pass<7>(g, Xb, WP7(M_FX), wm, l15, lg);
    #pragma unroll
    for (int mi = 0; mi < 2; ++mi)
        #pragma unroll
        for (int ni = 0; ni < 7; ++ni) {
            const int col = wn * 112 + ni * 16 + l15;
            const float b = (col < DDIM) ? fxb[col] : 0.0f;
            fxr[mi][ni][0] = cvtpk(g[mi][ni][0] + b, g[mi][ni][1] + b);
            fxr[mi][ni][1] = cvtpk(g[mi][ni][2] + b, g[mi][ni][3] + b);
        }

    // ==== FH x4 (GA pipeline): csum = sum_c sgm(ch_c@fh^T + fhb + fx) * chc_c ====
    float csum[2][7][4];
    #pragma unroll
    for (int mi = 0; mi < 2; ++mi)
        #pragma unroll
        for (int ni = 0; ni < 7; ++ni)
            #pragma unroll
            for (int j = 0; j < 4; ++j) csum[mi][ni][j] = 0.0f;

    #pragma unroll 1
    for (int c = 0; c < 4; ++c) {
        Z27(g);
        ga_pass(g, chh, row0, c * 200, WP7(M_FH), Ab, wv, lane, wm, l15, lg);
        #pragma unroll
        for (int mi = 0; mi < 2; ++mi)
            #pragma unroll
            for (int ni = 0; ni < 7; ++ni) {
                const int col = wn * 112 + ni * 16 + l15;
                if (col < DDIM) {
                    const float fb = fhb[col];
                    #pragma unroll
                    for (int j = 0; j < 4; ++j) {
                        long rg = row0 + wm * 32 + mi * 16 + lg * 4 + j;
                        if (rg >= NNODES) rg = NNODES - 1;
                        const float cv = chc[rg * 800 + c * 200 + col];
                        const unsigned pk = fxr[mi][ni][j >> 1];
                        const float fx = (j & 1) ? b2f_hi(pk) : b2f_lo(pk);
                        csum[mi][ni][j] += sgm(g[mi][ni][j] + fb + fx) * cv;
                    }
                }
            }
    }

    // ==== P1 (3 GA passes, accumulate): control = relu(sum_c ch_c@p1c^T + b) -> Hb ====
    {
        f32x4 p1[2][7];
        Z27(p1);
        ga_pass(p1, chh, row0, 0,   WP7(M_P1C0), Ab, wv, lane, wm, l15, lg);
        ga_pass(p1, chh, row0, 200, WP7(M_P1C1), Ab, wv, lane, wm, l15, lg);
        ga_pass(p1, chh, row0, 400, WP7(M_P1C2), Ab, wv, lane, wm, l15, lg);
        #pragma unroll
        for (int mi = 0; mi < 2; ++mi)
            #pragma unroll
            for (int ni = 0; ni < 7; ++ni) {
                const int col = wn * 112 + ni * 16 + l15;
                if (col < DDIM) {
                    const float b = p1b_[col];
                    #pragma unroll
                    for (int j = 0; j < 4; ++j) {
                        const int lr = wm * 32 + mi * 16 + lg * 4 + j;
                        Hb[lr * XP + col] = f2b1(fmaxf(p1[mi][ni][j] + b, 0.0f));
                    }
                }
            }
    }
    __syncthreads();   // control visible

    // ==== P2: hs = relu(ch3@p2b^T + control@p2a^T + b) -> Hb ====
    {
        f32x4 p2[2][7];
        Z27(p2);
        ga_pass(p2, chh, row0, 600, WP7(M_P2B), Ab, wv, lane, wm, l15, lg);
        la_pass<7>(p2, Hb, WP7(M_P2A), wm, l15, lg);
        __syncthreads();   // all control reads done before overwrite
        #pragma unroll
        for (int mi = 0; mi < 2; ++mi)
            #pragma unroll
            for (int ni = 0; ni < 7; ++ni) {
                const int col = wn * 112 + ni * 16 + l15;
                if (col < DDIM) {
                    const float b = p2b_[col];
                    #pragma unroll
                    for (int j = 0; j < 4; ++j) {
                        const int lr = wm * 32 + mi * 16 + lg * 4 + j;
                        Hb[lr * XP + col] = f2b1(fmaxf(p2[mi][ni][j] + b, 0.0f));
                    }
                }
            }
    }
    __syncthreads();   // hs visible

    // ==== I gate ====
    unsigned gi[2][7][2];
    Z27(g);
    la_pass<7>(g, Xb, WP7(M_IX), wm, l15, lg);
    la_pass<7>(g, Hb, WP7(M_IH), wm, l15, lg);
    #pragma unroll
    for (int mi = 0; mi < 2; ++mi)
        #pragma unroll
        for (int ni = 0; ni < 7; ++ni) {
            const int col = wn * 112 + ni * 16 + l15;
            const float b = (col < DDIM) ? (ixb[col] + ihb[col]) : 0.0f;
            gi[mi][ni][0] = cvtpk(sgm(g[mi][ni][0] + b), sgm(g[mi][ni][1] + b));
            gi[mi][ni][1] = cvtpk(sgm(g[mi][ni][2] + b), sgm(g[mi][ni][3] + b));
        }

    // ==== U gate: csum <- i*tanh(u) + csum  (= c value) ====
    Z27(g);
    la_pass<7>(g, Xb, WP7(M_UX), wm, l15, lg);
    la_pass<7>(g, Hb, WP7(M_UH), wm, l15, lg);
    #pragma unroll
    for (int mi = 0; mi < 2; ++mi)
        #pragma unroll
        for (int ni = 0; ni < 7; ++ni) {
            const int col = wn * 112 + ni * 16 + l15;
            const float b = (col < DDIM) ? (uxb[col] + uhb[col]) : 0.0f;
            #pragma unroll
            for (int j = 0; j < 4; ++j) {
                const unsigned pk = gi[mi][ni][j >> 1];
                const float iv = (j & 1) ? b2f_hi(pk) : b2f_lo(pk);
                csum[mi][ni][j] = iv * tanh_fast(g[mi][ni][j] + b) + csum[mi][ni][j];
            }
        }

    // ==== O gate: h = sgm(o)*tanh(c) -> Hb ====
    Z27(g);
    la_pass<7>(g, Xb, WP7(M_OX), wm, l15, lg);
    la_pass<7>(g, Hb, WP7(M_OH), wm, l15, lg);
    __syncthreads();   // all hs reads done before overwrite
    #pragma unroll
    for (int mi = 0; mi < 2; ++mi)
        #pragma unroll
        for (int ni = 0; ni < 7; ++ni) {
            const int col = wn * 112 + ni * 16 + l15;
            if (col < DDIM) {
                const float b = oxb[col] + ohb[col];
                #pragma unroll
                for (int j = 0; j < 4; ++j) {
                    const int lr = wm * 32 + mi * 16 + lg * 4 + j;
                    Hb[lr * XP + col] = f2b1(sgm(g[mi][ni][j] + b) * tanh_fast(csum[mi][ni][j]));
                }
            }
        }
    __syncthreads();   // h visible

    // ==== FC2: logits = h @ fc2^T + b -> out ====
    {
        f32x4 o8[2][8];
        #pragma unroll
        for (int mi = 0; mi < 2; ++mi)
            #pragma unroll
            for (int ni = 0; ni < 8; ++ni)
                #pragma unroll
                for (int q = 0; q < 4; ++q) o8[mi][ni][q] = 0.0f;
        la_pass<8>(o8, Hb, WP8(M_FC2), wm, l15, lg);
        #pragma unroll
        for (int mi = 0; mi < 2; ++mi)
            #pragma unroll
            for (int ni = 0; ni < 8; ++ni) {
                const int col = wn * 128 + ni * 16 + l15;
                if (col < NCLS) {
                    const float b = fc2b[col];
                    #pragma unroll
                    for (int j = 0; j < 4; ++j) {
                        const long gr = row0 + wm * 32 + mi * 16 + lg * 4 + j;
                        if (gr < NNODES) out[gr * NCLS + col] = o8[mi][ni][j] + b;
                    }
                }
            }
    }
    #undef WP7
    #undef WP8
}

// ================= fallback fp32 kernel (used only if ws too small) =================
constexpr int FRT = 32, FBK = 16, FNT = 256, FRTP = FRT + 4, FBUFP = 208;
__device__ __forceinline__ float sgm_f(float x) { return 1.0f / (1.0f + expf(-x)); }

__device__ __forceinline__ void f_stage(
    float (*aT)[FRTP], float (*wt)[FNT], int row0, int k0,
    const float* a1g, int a1pitch, const int* gidx, const float* a1l, int a1lp, int K1,
    const float* a2g, int a2pitch, const float* a2l, int a2lp, int K2,
    const float* wa, int wap, int KW1, const float* wb, int wbp,
    int ncols, int tid)
{
    const int Ktot = K1 + K2;
    {
        const int kk = tid & 15, k = k0 + kk;
        #pragma unroll
        for (int h = 0; h < 2; ++h) {
            const int r = (tid >> 4) + h * 16;
            float v = 0.0f;
            if (k < K1) {
                if (a1l) v = a1l[r * a1lp + k];
                else {
                    const long rb = gidx ? (long)gidx[row0 + r] * a1pitch : (long)(row0 + r) * a1pitch;
                    v = a1g[rb + k];
                }
            } else if (k < Ktot) {
                if (a2l) v = a2l[r * a2lp + (k - K1)];
                else     v = a2g[(long)(row0 + r) * a2pitch + (k - K1)];
            }
            aT[kk][r] = v;
        }
    }
    {
        const int col = tid;
        #pragma unroll
        for (int kk = 0; kk < FBK; ++kk) {
            const int k = k0 + kk; float v = 0.0f;
            if (col < ncols && k < Ktot) {
                if (k < KW1) v = wa[(long)col * wap + k];
                else         v = wb[(long)col * wbp + (k - KW1)];
            }
            wt[kk][col] = v;
        }
    }
}
__device__ __forceinline__ void f_gemm(
    float (*aT)[FRTP], float (*wt)[FNT], float acc[8][4], int row0,
    const float* a1g, int a1p, const int* gidx, const float* a1l, int a1lp, int K1,
    const float* a2g, int a2p, const float* a2l, int a2lp, int K2,
    const float* wa, int wap, int KW1, const float* wb, int wbp,
    int ncols, int tid, int tr, int tc)
{
    #pragma unroll
    for (int j = 0; j < 8; ++j)
        #pragma unroll
        for (int i = 0; i < 4; ++i) acc[j][i] = 0.0f;
    const int Ktot = K1 + K2;
    for (int k0 = 0; k0 < Ktot; k0 += FBK) {
        __syncthreads();
        f_stage(aT, wt, row0, k0, a1g, a1p, gidx, a1l, a1lp, K1, a2g, a2p, a2l, a2lp, K2,
                wa, wap, KW1, wb, wbp, ncols, tid);
        __syncthreads();
        #pragma unroll
        for (int kk = 0; kk < FBK; ++kk) {
            const float w0 = wt[kk][tc*4+0], w1 = wt[kk][tc*4+1], w2 = wt[kk][tc*4+2], w3 = wt[kk][tc*4+3];
            #pragma unroll
            for (int j = 0; j < 8; ++j) {
                const float a = aT[kk][tr*8+j];
                acc[j][0] = fmaf(a, w0, acc[j][0]); acc[j][1] = fmaf(a, w1, acc[j][1]);
                acc[j][2] = fmaf(a, w2, acc[j][2]); acc[j][3] = fmaf(a, w3, acc[j][3]);
            }
        }
    }
}
__global__ __launch_bounds__(256)
void fused_fp32(const int* tok, const float* chc, const float* chh, const float* emb,
                const float* p1w, const float* p1b, const float* p2w, const float* p2b,
                const float* ixw, const float* ixb, const float* ihw, const float* ihb,
                const float* fxw, const float* fxb, const float* fhw, const float* fhb,
                const float* uxw, const float* uxb, const float* uhw, const float* uhb,
                const float* oxw, const float* oxb, const float* ohw, const float* ohb,
                const float* fc2w, const float* fc2b, float* out)
{
    __shared__ float aT[FBK][FRTP]; __shared__ float wt[FBK][FNT]; __shared__ float buf[FRT][FBUFP];
    const int tid = threadIdx.x, tr = tid >> 6, tc = tid & 63, c0 = tc * 4;
    const int row0 = blockIdx.x * FRT;
    float acc[8][4];
    f_gemm(aT, wt, acc, row0, chh, 800, nullptr, nullptr, 0, 600, nullptr,0,nullptr,0,0, p1w,600,600,nullptr,0, DDIM, tid,tr,tc);
    if (c0 < DDIM) { const float4 b = *(const float4*)&p1b[c0];
        #pragma unroll
        for (int j=0;j<8;++j){int r=tr*8+j; buf[r][c0]=fmaxf(acc[j][0]+b.x,0.f); buf[r][c0+1]=fmaxf(acc[j][1]+b.y,0.f); buf[r][c0+2]=fmaxf(acc[j][2]+b.z,0.f); buf[r][c0+3]=fmaxf(acc[j][3]+b.w,0.f);} }
    f_gemm(aT, wt, acc, row0, nullptr,0,nullptr,&buf[0][0],FBUFP,200, chh+600,800,nullptr,0,200, p2w,400,400,nullptr,0, DDIM, tid,tr,tc);
    if (c0 < DDIM) { const float4 b = *(const float4*)&p2b[c0];
        #pragma unroll
        for (int j=0;j<8;++j){int r=tr*8+j; buf[r][c0]=fmaxf(acc[j][0]+b.x,0.f); buf[r][c0+1]=fmaxf(acc[j][1]+b.y,0.f); buf[r][c0+2]=fmaxf(acc[j][2]+b.z,0.f); buf[r][c0+3]=fmaxf(acc[j][3]+b.w,0.f);} }
    f_gemm(aT, wt, acc, row0, emb, DDIM, tok, nullptr,0,200, nullptr,0,nullptr,0,0, fxw,200,200,nullptr,0, DDIM, tid,tr,tc);
    float fxr[8][4];
    { float4 b = make_float4(0,0,0,0); if (c0<DDIM) b = *(const float4*)&fxb[c0];
      #pragma unroll
      for (int j=0;j<8;++j){fxr[j][0]=acc[j][0]+b.x;fxr[j][1]=acc[j][1]+b.y;fxr[j][2]=acc[j][2]+b.z;fxr[j][3]=acc[j][3]+b.w;} }
    float csum[8][4];
    #pragma unroll
    for (int j=0;j<8;++j)
        #pragma unroll
        for (int i=0;i<4;++i) csum[j][i]=0.f;
    for (int cc_=0; cc_<4; ++cc_) {
        f_gemm(aT, wt, acc, row0, chh+cc_*200,800,nullptr,nullptr,0,200, nullptr,0,nullptr,0,0, fhw,200,200,nullptr,0, DDIM, tid,tr,tc);
        if (c0 < DDIM) { const float4 b = *(const float4*)&fhb[c0];
            #pragma unroll
            for (int j=0;j<8;++j){ const long r=row0+tr*8+j; const float4 cv=*(const float4*)&chc[r*800+cc_*200+c0];
                csum[j][0]+=sgm_f(acc[j][0]+b.x+fxr[j][0])*cv.x; csum[j][1]+=sgm_f(acc[j][1]+b.y+fxr[j][1])*cv.y;
                csum[j][2]+=sgm_f(acc[j][2]+b.z+fxr[j][2])*cv.z; csum[j][3]+=sgm_f(acc[j][3]+b.w+fxr[j][3])*cv.w; } }
    }
    f_gemm(aT, wt, acc, row0, emb, DDIM, tok, nullptr,0,200, nullptr,0,&buf[0][0],FBUFP,200, ixw,200,200,ihw,200, DDIM, tid,tr,tc);
    float gi[8][4];
    { float4 b1=make_float4(0,0,0,0),b2=b1; if(c0<DDIM){b1=*(const float4*)&ixb[c0];b2=*(const float4*)&ihb[c0];}
      #pragma unroll
      for(int j=0;j<8;++j){gi[j][0]=sgm_f(acc[j][0]+b1.x+b2.x);gi[j][1]=sgm_f(acc[j][1]+b1.y+b2.y);gi[j][2]=sgm_f(acc[j][2]+b1.z+b2.z);gi[j][3]=sgm_f(acc[j][3]+b1.w+b2.w);} }
    f_gemm(aT, wt, acc, row0, emb, DDIM, tok, nullptr,0,200, nullptr,0,&buf[0][0],FBUFP,200, uxw,200,200,uhw,200, DDIM, tid,tr,tc);
    float cval[8][4];
    { float4 b1=make_float4(0,0,0,0),b2=b1; if(c0<DDIM){b1=*(const float4*)&uxb[c0];b2=*(const float4*)&uhb[c0];}
      #pragma unroll
      for(int j=0;j<8;++j){cval[j][0]=gi[j][0]*tanhf(acc[j][0]+b1.x+b2.x)+csum[j][0];cval[j][1]=gi[j][1]*tanhf(acc[j][1]+b1.y+b2.y)+csum[j][1];
                           cval[j][2]=gi[j][2]*tanhf(acc[j][2]+b1.z+b2.z)+csum[j][2];cval[j][3]=gi[j][3]*tanhf(acc[j][3]+b1.w+b2.w)+csum[j][3];} }
    f_gemm(aT, wt, acc, row0, emb, DDIM, tok, nullptr,0,200, nullptr,0,&buf[0][0],FBUFP,200, oxw,200,200,ohw,200, DDIM, tid,tr,tc);
    if (c0 < DDIM) { const float4 b1=*(const float4*)&oxb[c0], b2=*(const float4*)&ohb[c0];
        #pragma unroll
        for(int j=0;j<8;++j){int r=tr*8+j;
            buf[r][c0]=sgm_f(acc[j][0]+b1.x+b2.x)*tanhf(cval[j][0]); buf[r][c0+1]=sgm_f(acc[j][1]+b1.y+b2.y)*tanhf(cval[j][1]);
            buf[r][c0+2]=sgm_f(acc[j][2]+b1.z+b2.z)*tanhf(cval[j][2]); buf[r][c0+3]=sgm_f(acc[j][3]+b1.w+b2.w)*tanhf(cval[j][3]);} }
    f_gemm(aT, wt, acc, row0, nullptr,0,nullptr,&buf[0][0],FBUFP,200, nullptr,0,nullptr,0,0, fc2w,200,200,nullptr,0, NCLS, tid,tr,tc);
    #pragma unroll
    for (int j=0;j<8;++j){ const long r=row0+tr*8+j;
        #pragma unroll
        for (int i=0;i<4;++i){ const int col=c0+i; if (col<NCLS) out[r*NCLS+col]=acc[j][i]+fc2b[col]; } }
}

// ================= launch =================
extern "C" void kernel_launch(void* const* d_in, const int* in_sizes, int n_in,
                              void* d_out, int out_size, void* d_ws, size_t ws_size,
                              hipStream_t stream)
{
    const int*   tok  = (const int*)  d_in[0];
    const float* chc  = (const float*)d_in[1];
    const float* chh  = (const float*)d_in[2];
    const float* emb  = (const float*)d_in[3];
    const float* p1w  = (const float*)d_in[4];
    const float* p1b  = (const float*)d_in[5];
    const float* p2w  = (const float*)d_in[6];
    const float* p2b  = (const float*)d_in[7];
    const float* ixw  = (const float*)d_in[8];
    const float* ixb  = (const float*)d_in[9];
    const float* ihw  = (const float*)d_in[10];
    const float* ihb  = (const float*)d_in[11];
    const float* fxw  = (const float*)d_in[12];
    const float* fxb  = (const float*)d_in[13];
    const float* fhw  = (const float*)d_in[14];
    const float* fhb  = (const float*)d_in[15];
    const float* uxw  = (const float*)d_in[16];
    const float* uxb  = (const float*)d_in[17];
    const float* uhw  = (const float*)d_in[18];
    const float* uhb  = (const float*)d_in[19];
    const float* oxw  = (const float*)d_in[20];
    const float* oxb  = (const float*)d_in[21];
    const float* ohw  = (const float*)d_in[22];
    const float* ohb  = (const float*)d_in[23];
    const float* fc2w = (const float*)d_in[24];
    const float* fc2b = (const float*)d_in[25];
    float* out = (float*)d_out;

    if (ws_size >= W_TOTAL_BYTES) {
        short* ws = (short*)d_ws;
        hipLaunchKernelGGL(wprep, dim3((W_TOTAL_ELEMS + 255) / 256), dim3(256), 0, stream,
                           p1w, p2w, fxw, fhw, ixw, ihw, uxw, uhw, oxw, ohw, fc2w, ws);
        hipLaunchKernelGGL(fused_v6, dim3((NNODES + ROWS - 1) / ROWS), dim3(256), 0, stream,
                           tok, chc, chh, emb,
                           p1b, p2b, ixb, ihb, fxb, fhb, uxb, uhb, oxb, ohb, fc2b,
                           ws, out);
    } else {
        hipLaunchKernelGGL(fused_fp32, dim3(NNODES / FRT), dim3(256), 0, stream,
                           tok, chc, chh, emb, p1w, p1b, p2w, p2b,
                           ixw, ixb, ihw, ihb, fxw, fxb, fhw, fhb,
                           uxw, uxb, uhw, uhb, oxw, oxb, ohw, ohb, fc2w, fc2b, out);
    }
}

// Round 10
// 449.842 us; speedup vs baseline: 2.1935x; 1.3939x over previous
//
#include <hip/hip_runtime.h>
#include <cmath>

#define NNODES 60000
#define DDIM   200
#define NCLS   250

constexpr int R   = 32;        // rows per block -> 1875 blocks exact
constexpr int BK  = 32;        // K per MFMA step
constexpr int XP  = 208;       // act pitch (shorts)

// LDS arena (shorts): X | H | a_sw(2x1024) | w_sw(2x8192) | pad
constexpr int O_X  = 0;
constexpr int O_H  = R * XP;                 // 6656
constexpr int O_A  = 2 * R * XP;             // 13312
constexpr int AS   = R * BK;                 // 1024 shorts per a buf
constexpr int O_W  = O_A + 2 * AS;           // 15360
constexpr int WS   = 8192;                   // shorts per w buf (16KB)
constexpr int SH_TOT = O_W + 2 * WS + 32;    // 31776 shorts = 63.5KB

typedef float  f32x4  __attribute__((ext_vector_type(4)));
typedef short  short8 __attribute__((ext_vector_type(8)));

// ---- ws layout (R3-verified): W_P1 [256][608]; 11 mats [256][224]
constexpr int W_P1  = 0;
constexpr int W_P2A = 155648;
constexpr int W_P2B = 212992;
constexpr int W_FX  = 270336;
constexpr int W_FH  = 327680;
constexpr int W_IX  = 385024;
constexpr int W_IH  = 442368;
constexpr int W_UX  = 499712;
constexpr int W_UH  = 557056;
constexpr int W_OX  = 614400;
constexpr int W_OH  = 671744;
constexpr int W_FC2 = 729088;
constexpr int W_TOTAL_ELEMS = 786432;
constexpr size_t W_TOTAL_BYTES = (size_t)W_TOTAL_ELEMS * 2;

__device__ __forceinline__ short f2b(float f) {
    union { float f; unsigned u; } x; x.f = f;
    unsigned r = (x.u + 0x7FFFu + ((x.u >> 16) & 1u)) >> 16;   // RNE
    return (short)r;
}
__device__ __forceinline__ unsigned cvtpk(float lo, float hi) {
    unsigned r; asm("v_cvt_pk_bf16_f32 %0, %1, %2" : "=v"(r) : "v"(lo), "v"(hi));
    return r;
}
__device__ __forceinline__ short f2b1(float f) { return (short)(cvtpk(f, f) & 0xffffu); }
__device__ __forceinline__ float b2f(short s) {
    union { unsigned u; float f; } x; x.u = ((unsigned)(unsigned short)s) << 16;
    return x.f;
}
__device__ __forceinline__ float b2f_lo(unsigned u) { return b2f((short)(u & 0xffffu)); }
__device__ __forceinline__ float b2f_hi(unsigned u) { return b2f((short)(u >> 16)); }
__device__ __forceinline__ float sgm(float x)  { return 1.0f / (1.0f + __expf(-x)); }
__device__ __forceinline__ float tanh_fast(float x) { return 1.0f - 2.0f / (__expf(2.0f * x) + 1.0f); }
__device__ __forceinline__ int   swz(int b)    { return b ^ (((b >> 7) & 3) << 4); }
__device__ __forceinline__ short8 cvt8(float4 f0, float4 f1) {
    union { unsigned u[4]; short8 s; } c;
    c.u[0] = cvtpk(f0.x, f0.y); c.u[1] = cvtpk(f0.z, f0.w);
    c.u[2] = cvtpk(f1.x, f1.y); c.u[3] = cvtpk(f1.z, f1.w);
    return c.s;
}

// ================= weight prepass (R3 verbatim — verified) =================
__global__ void wprep(const float* __restrict__ p1w, const float* __restrict__ p2w,
                      const float* __restrict__ fxw, const float* __restrict__ fhw,
                      const float* __restrict__ ixw, const float* __restrict__ ihw,
                      const float* __restrict__ uxw, const float* __restrict__ uhw,
                      const float* __restrict__ oxw, const float* __restrict__ ohw,
                      const float* __restrict__ fc2w, short* __restrict__ ws)
{
    int i = blockIdx.x * 256 + threadIdx.x;
    if (i >= W_TOTAL_ELEMS) return;
    float v = 0.0f;
    if (i < W_P2A) {                       // p1: [256][608], src 200x600
        int n = i / 608, k = i % 608;
        if (n < 200 && k < 600) v = p1w[n * 600 + k];
        ws[i] = f2b(v); return;
    }
    int j = i - W_P2A;
    int m = j / 57344, rem = j % 57344;
    int n = rem / 224, k = rem % 224;
    const float* src; int stride = 200, off = 0, ncols = 200;
    switch (m) {
        case 0:  src = p2w; stride = 400; break;
        case 1:  src = p2w; stride = 400; off = 200; break;
        case 2:  src = fxw; break;
        case 3:  src = fhw; break;
        case 4:  src = ixw; break;
        case 5:  src = ihw; break;
        case 6:  src = uxw; break;
        case 7:  src = uhw; break;
        case 8:  src = oxw; break;
        case 9:  src = ohw; break;
        default: src = fc2w; ncols = 250; break;
    }
    if (n < ncols && k < 200) v = src[n * stride + off + k];
    ws[i] = f2b(v);
}

// ================= staging (R3-verified addressing) =================
__device__ __forceinline__ void gload16(const void* g, void* l) {
    __builtin_amdgcn_global_load_lds((const __attribute__((address_space(1))) unsigned*)g,
                                     (__attribute__((address_space(3))) unsigned*)l, 16, 0, 0);
}

__device__ __forceinline__ void stage_w(const short* __restrict__ wmat, int Kpad, int t,
                                        int wrows, int wv, short* w_sw)
{
    const int issues = wrows >> 4;               // 1KB per issue
    for (int q = wv; q < issues; q += 4) {
        const int lane = threadIdx.x & 63;
        const int db = q * 1024 + lane * 16;     // linear dest byte
        const int n  = db >> 6;
        const int g  = (db >> 4) & 3;
        const int gs = g ^ ((n >> 1) & 3);       // inverse swizzle on source
        const short* src = wmat + (long)n * Kpad + t * BK + gs * 8;
        char* dst = ((char*)w_sw) + q * 1024;
        gload16(src, dst);
    }
}

__device__ __forceinline__ void stage_a_chh(short* a_sw, const float* __restrict__ ag,
                                            int row0, int colofs, int k0, int Kreal, int tid)
{
    if (tid >= 4 * R) return;                    // 128 workers: 32 rows x 4 chunks
    const int r = tid >> 2, gq = tid & 3;
    const float* src = ag + (long)(row0 + r) * 800 + colofs + k0 + gq * 8;
    short8 v;
    if (k0 + BK <= Kreal) {
        float4 f0 = *(const float4*)(src);
        float4 f1 = *(const float4*)(src + 4);
        v = cvt8(f0, f1);
    } else {
        #pragma unroll
        for (int i = 0; i < 8; ++i) {
            int k = k0 + gq * 8 + i;
            float f = (k < Kreal) ? src[i] : 0.0f;
            v[i] = f2b(f);
        }
    }
    int b = r * 64 + gq * 16; b = swz(b);
    *(short8*)((char*)a_sw + b) = v;
}

// ================= GEMM pass: min-2-phase dbuf (stage t+1 BEFORE compute t) =================
template<int NF, bool FROM_GLOBAL>
__device__ __forceinline__ void gemm_pass(
    f32x4 (&acc)[NF],
    const short* __restrict__ Ap,                // act base (LA) , pitch XP
    const float* __restrict__ ag, int row0, int colofs, int Kreal,
    const short* __restrict__ wmat, int ktiles, int Kpad, int wrows,
    short* a_sw, short* w_sw,
    int tid, int wv, int wm, int wn, int l15, int lg)
{
    stage_w(wmat, Kpad, 0, wrows, wv, w_sw);
    if constexpr (FROM_GLOBAL)
        stage_a_chh(a_sw, ag, row0, colofs, 0, Kreal, tid);
    asm volatile("s_waitcnt vmcnt(0) lgkmcnt(0)" ::: "memory");
    __builtin_amdgcn_s_barrier();
    for (int t = 0; t < ktiles; ++t) {
        const int cur = t & 1, nxt = cur ^ 1;
        if (t + 1 < ktiles) {                    // issue next-tile stage first
            stage_w(wmat, Kpad, t + 1, wrows, wv, w_sw + nxt * WS);
            if constexpr (FROM_GLOBAL)
                stage_a_chh(a_sw + nxt * AS, ag, row0, colofs, (t + 1) * BK, Kreal, tid);
        }
        short8 af;
        const int row = wm * 16 + l15;
        if constexpr (FROM_GLOBAL)
            af = *(const short8*)((const char*)(a_sw + cur * AS) + swz(row * 64 + lg * 16));
        else
            af = *(const short8*)(Ap + row * XP + t * BK + lg * 8);
        #pragma unroll
        for (int ni = 0; ni < NF; ++ni) {
            const int n = (wn * NF + ni) * 16 + l15;
            short8 bf = *(const short8*)((const char*)(w_sw + cur * WS) + swz(n * 64 + lg * 16));
            acc[ni] = __builtin_amdgcn_mfma_f32_16x16x32_bf16(af, bf, acc[ni], 0, 0, 0);
        }
        asm volatile("s_waitcnt vmcnt(0) lgkmcnt(0)" ::: "memory");
        __builtin_amdgcn_s_barrier();            // next buf staged; cur buf free
    }
}

#define Z7(A)  { _Pragma("unroll") for (int z_=0; z_<7; ++z_) { _Pragma("unroll") for (int q_=0;q_<4;++q_) A[z_][q_] = 0.0f; } }
#define Z8(A)  { _Pragma("unroll") for (int z_=0; z_<8; ++z_) { _Pragma("unroll") for (int q_=0;q_<4;++q_) A[z_][q_] = 0.0f; } }

__global__ __launch_bounds__(256, 2)
void fused_v7(const int* __restrict__ tok,
              const float* __restrict__ chc,
              const float* __restrict__ chh,
              const float* __restrict__ emb,
              const float* __restrict__ p1b_, const float* __restrict__ p2b_,
              const float* __restrict__ ixb, const float* __restrict__ ihb,
              const float* __restrict__ fxb, const float* __restrict__ fhb,
              const float* __restrict__ uxb, const float* __restrict__ uhb,
              const float* __restrict__ oxb, const float* __restrict__ ohb,
              const float* __restrict__ fc2b,
              const short* __restrict__ ws,
              float* __restrict__ out)
{
    __shared__ __align__(16) short SH[SH_TOT];
    short* X    = SH + O_X;      // x
    short* H    = SH + O_H;      // control -> hs -> h
    short* a_sw = SH + O_A;      // 2 x 2KB
    short* w_sw = SH + O_W;      // 2 x 16KB

    const int tid = threadIdx.x;
    const int wv = tid >> 6, wm = wv >> 1, wn = wv & 1;
    const int l15 = tid & 15, lg = (tid & 63) >> 4;
    const int row0 = blockIdx.x * R;

    // ---- zero arena, stage x ----
    {
        short8 z = (short8)0;
        short8* shv = (short8*)SH;
        #pragma unroll 1
        for (int i = tid; i < SH_TOT / 8; i += 256) shv[i] = z;
    }
    __syncthreads();
    {
        #pragma unroll
        for (int it = 0; it < 4; ++it) {
            int u = tid + it * 256;
            if (u < 800) {                       // 32 rows x 25 chunks of 8 cols
                int r = u / 25, cu = (u % 25) * 8;
                const float* s = emb + (long)tok[row0 + r] * DDIM + cu;
                float4 f0 = *(const float4*)s, f1 = *(const float4*)(s + 4);
                *(short8*)(X + r * XP + cu) = cvt8(f0, f1);
            }
        }
    }
    __syncthreads();

    f32x4 g[7];

    // ==== FX: fxr = x @ fx^T + b (bf16-packed regs) ====
    unsigned fxr[7][2];
    Z7(g);
    gemm_pass<7, false>(g, X, nullptr, 0, 0, 0, ws + W_FX, 7, 224, 224,
                        a_sw, w_sw, tid, wv, wm, wn, l15, lg);
    #pragma unroll
    for (int ni = 0; ni < 7; ++ni) {
        const int col = (wn * 7 + ni) * 16 + l15;
        const float b = (col < DDIM) ? fxb[col] : 0.0f;
        fxr[ni][0] = cvtpk(g[ni][0] + b, g[ni][1] + b);
        fxr[ni][1] = cvtpk(g[ni][2] + b, g[ni][3] + b);
    }

    // ==== FH x4: csum = sum_c sgm(ch_c@fh^T + fhb + fx) * chc_c ====
    float csum[7][4];
    #pragma unroll
    for (int ni = 0; ni < 7; ++ni)
        #pragma unroll
        for (int j = 0; j < 4; ++j) csum[ni][j] = 0.0f;

    #pragma unroll 1
    for (int c = 0; c < 4; ++c) {
        Z7(g);
        gemm_pass<7, true>(g, nullptr, chh, row0, c * 200, 200, ws + W_FH, 7, 224, 224,
                           a_sw, w_sw, tid, wv, wm, wn, l15, lg);
        #pragma unroll
        for (int ni = 0; ni < 7; ++ni) {
            const int col = (wn * 7 + ni) * 16 + l15;
            if (col < DDIM) {
                const float fb = fhb[col];
                #pragma unroll
                for (int j = 0; j < 4; ++j) {
                    const int lr = wm * 16 + lg * 4 + j;
                    const float cv = chc[(long)(row0 + lr) * 800 + c * 200 + col];
                    const unsigned pk = fxr[ni][j >> 1];
                    const float fx = (j & 1) ? b2f_hi(pk) : b2f_lo(pk);
                    csum[ni][j] += sgm(g[ni][j] + fb + fx) * cv;
                }
            }
        }
    }

    // ==== P1: control = relu([ch0|ch1|ch2] @ p1^T + b) -> H ====
    Z7(g);
    gemm_pass<7, true>(g, nullptr, chh, row0, 0, 600, ws + W_P1, 19, 608, 224,
                       a_sw, w_sw, tid, wv, wm, wn, l15, lg);
    #pragma unroll
    for (int ni = 0; ni < 7; ++ni) {
        const int col = (wn * 7 + ni) * 16 + l15;
        if (col < DDIM) {
            const float b = p1b_[col];
            #pragma unroll
            for (int j = 0; j < 4; ++j) {
                const int lr = wm * 16 + lg * 4 + j;
                H[lr * XP + col] = f2b1(fmaxf(g[ni][j] + b, 0.0f));
            }
        }
    }
    __syncthreads();   // control visible

    // ==== P2: hs = relu(control@p2a^T + ch3@p2b^T + b) -> H ====
    Z7(g);
    gemm_pass<7, false>(g, H, nullptr, 0, 0, 0, ws + W_P2A, 7, 224, 224,
                        a_sw, w_sw, tid, wv, wm, wn, l15, lg);
    gemm_pass<7, true>(g, nullptr, chh, row0, 600, 200, ws + W_P2B, 7, 224, 224,
                       a_sw, w_sw, tid, wv, wm, wn, l15, lg);
    // exit barrier of the passes guarantees all control reads finished
    #pragma unroll
    for (int ni = 0; ni < 7; ++ni) {
        const int col = (wn * 7 + ni) * 16 + l15;
        if (col < DDIM) {
            const float b = p2b_[col];
            #pragma unroll
            for (int j = 0; j < 4; ++j) {
                const int lr = wm * 16 + lg * 4 + j;
                H[lr * XP + col] = f2b1(fmaxf(g[ni][j] + b, 0.0f));
            }
        }
    }
    __syncthreads();   // hs visible

    // ==== I gate ====
    unsigned gi[7][2];
    Z7(g);
    gemm_pass<7, false>(g, X, nullptr, 0, 0, 0, ws + W_IX, 7, 224, 224,
                        a_sw, w_sw, tid, wv, wm, wn, l15, lg);
    gemm_pass<7, false>(g, H, nullptr, 0, 0, 0, ws + W_IH, 7, 224, 224,
                        a_sw, w_sw, tid, wv, wm, wn, l15, lg);
    #pragma unroll
    for (int ni = 0; ni < 7; ++ni) {
        const int col = (wn * 7 + ni) * 16 + l15;
        const float b = (col < DDIM) ? (ixb[col] + ihb[col]) : 0.0f;
        gi[ni][0] = cvtpk(sgm(g[ni][0] + b), sgm(g[ni][1] + b));
        gi[ni][1] = cvtpk(sgm(g[ni][2] + b), sgm(g[ni][3] + b));
    }

    // ==== U gate: csum <- i*tanh(u) + csum  (= c) ====
    Z7(g);
    gemm_pass<7, false>(g, X, nullptr, 0, 0, 0, ws + W_UX, 7, 224, 224,
                        a_sw, w_sw, tid, wv, wm, wn, l15, lg);
    gemm_pass<7, false>(g, H, nullptr, 0, 0, 0, ws + W_UH, 7, 224, 224,
                        a_sw, w_sw, tid, wv, wm, wn, l15, lg);
    #pragma unroll
    for (int ni = 0; ni < 7; ++ni) {
        const int col = (wn * 7 + ni) * 16 + l15;
        const float b = (col < DDIM) ? (uxb[col] + uhb[col]) : 0.0f;
        #pragma unroll
        for (int j = 0; j < 4; ++j) {
            const unsigned pk = gi[ni][j >> 1];
            const float iv = (j & 1) ? b2f_hi(pk) : b2f_lo(pk);
            csum[ni][j] = iv * tanh_fast(g[ni][j] + b) + csum[ni][j];
        }
    }

    // ==== O gate: h = sgm(o)*tanh(c) -> H ====
    Z7(g);
    gemm_pass<7, false>(g, X, nullptr, 0, 0, 0, ws + W_OX, 7, 224, 224,
                        a_sw, w_sw, tid, wv, wm, wn, l15, lg);
    gemm_pass<7, false>(g, H, nullptr, 0, 0, 0, ws + W_OH, 7, 224, 224,
                        a_sw, w_sw, tid, wv, wm, wn, l15, lg);
    // pass exit barrier covers all hs reads
    #pragma unroll
    for (int ni = 0; ni < 7; ++ni) {
        const int col = (wn * 7 + ni) * 16 + l15;
        if (col < DDIM) {
            const float b = oxb[col] + ohb[col];
            #pragma unroll
            for (int j = 0; j < 4; ++j) {
                const int lr = wm * 16 + lg * 4 + j;
                H[lr * XP + col] = f2b1(sgm(g[ni][j] + b) * tanh_fast(csum[ni][j]));
            }
        }
    }
    __syncthreads();   // h visible

    // ==== FC2: logits = h @ fc2^T + b -> out ====
    f32x4 o8[8];
    Z8(o8);
    gemm_pass<8, false>(o8, H, nullptr, 0, 0, 0, ws + W_FC2, 7, 224, 256,
                        a_sw, w_sw, tid, wv, wm, wn, l15, lg);
    #pragma unroll
    for (int ni = 0; ni < 8; ++ni) {
        const int col = (wn * 8 + ni) * 16 + l15;
        if (col < NCLS) {
            const float b = fc2b[col];
            #pragma unroll
            for (int j = 0; j < 4; ++j) {
                const int lr = wm * 16 + lg * 4 + j;
                out[(long)(row0 + lr) * NCLS + col] = o8[ni][j] + b;
            }
        }
    }
}

// ================= fallback fp32 kernel (used only if ws too small) =================
constexpr int FRT = 32, FBK = 16, FNT = 256, FRTP = FRT + 4, FBUFP = 208;
__device__ __forceinline__ float sgm_f(float x) { return 1.0f / (1.0f + expf(-x)); }

__device__ __forceinline__ void f_stage(
    float (*aT)[FRTP], float (*wt)[FNT], int row0, int k0,
    const float* a1g, int a1pitch, const int* gidx, const float* a1l, int a1lp, int K1,
    const float* a2g, int a2pitch, const float* a2l, int a2lp, int K2,
    const float* wa, int wap, int KW1, const float* wb, int wbp,
    int ncols, int tid)
{
    const int Ktot = K1 + K2;
    {
        const int kk = tid & 15, k = k0 + kk;
        #pragma unroll
        for (int h = 0; h < 2; ++h) {
            const int r = (tid >> 4) + h * 16;
            float v = 0.0f;
            if (k < K1) {
                if (a1l) v = a1l[r * a1lp + k];
                else {
                    const long rb = gidx ? (long)gidx[row0 + r] * a1pitch : (long)(row0 + r) * a1pitch;
                    v = a1g[rb + k];
                }
            } else if (k < Ktot) {
                if (a2l) v = a2l[r * a2lp + (k - K1)];
                else     v = a2g[(long)(row0 + r) * a2pitch + (k - K1)];
            }
            aT[kk][r] = v;
        }
    }
    {
        const int col = tid;
        #pragma unroll
        for (int kk = 0; kk < FBK; ++kk) {
            const int k = k0 + kk; float v = 0.0f;
            if (col < ncols && k < Ktot) {
                if (k < KW1) v = wa[(long)col * wap + k];
                else         v = wb[(long)col * wbp + (k - KW1)];
            }
            wt[kk][col] = v;
        }
    }
}
__device__ __forceinline__ void f_gemm(
    float (*aT)[FRTP], float (*wt)[FNT], float acc[8][4], int row0,
    const float* a1g, int a1p, const int* gidx, const float* a1l, int a1lp, int K1,
    const float* a2g, int a2p, const float* a2l, int a2lp, int K2,
    const float* wa, int wap, int KW1, const float* wb, int wbp,
    int ncols, int tid, int tr, int tc)
{
    #pragma unroll
    for (int j = 0; j < 8; ++j)
        #pragma unroll
        for (int i = 0; i < 4; ++i) acc[j][i] = 0.0f;
    const int Ktot = K1 + K2;
    for (int k0 = 0; k0 < Ktot; k0 += FBK) {
        __syncthreads();
        f_stage(aT, wt, row0, k0, a1g, a1p, gidx, a1l, a1lp, K1, a2g, a2p, a2l, a2lp, K2,
                wa, wap, KW1, wb, wbp, ncols, tid);
        __syncthreads();
        #pragma unroll
        for (int kk = 0; kk < FBK; ++kk) {
            const float w0 = wt[kk][tc*4+0], w1 = wt[kk][tc*4+1], w2 = wt[kk][tc*4+2], w3 = wt[kk][tc*4+3];
            #pragma unroll
            for (int j = 0; j < 8; ++j) {
                const float a = aT[kk][tr*8+j];
                acc[j][0] = fmaf(a, w0, acc[j][0]); acc[j][1] = fmaf(a, w1, acc[j][1]);
                acc[j][2] = fmaf(a, w2, acc[j][2]); acc[j][3] = fmaf(a, w3, acc[j][3]);
            }
        }
    }
}
__global__ __launch_bounds__(256)
void fused_fp32(const int* tok, const float* chc, const float* chh, const float* emb,
                const float* p1w, const float* p1b, const float* p2w, const float* p2b,
                const float* ixw, const float* ixb, const float* ihw, const float* ihb,
                const float* fxw, const float* fxb, const float* fhw, const float* fhb,
                const float* uxw, const float* uxb, const float* uhw, const float* uhb,
                const float* oxw, const float* oxb, const float* ohw, const float* ohb,
                const float* fc2w, const float* fc2b, float* out)
{
    __shared__ float aT[FBK][FRTP]; __shared__ float wt[FBK][FNT]; __shared__ float buf[FRT][FBUFP];
    const int tid = threadIdx.x, tr = tid >> 6, tc = tid & 63, c0 = tc * 4;
    const int row0 = blockIdx.x * FRT;
    float acc[8][4];
    f_gemm(aT, wt, acc, row0, chh, 800, nullptr, nullptr, 0, 600, nullptr,0,nullptr,0,0, p1w,600,600,nullptr,0, DDIM, tid,tr,tc);
    if (c0 < DDIM) { const float4 b = *(const float4*)&p1b[c0];
        #pragma unroll
        for (int j=0;j<8;++j){int r=tr*8+j; buf[r][c0]=fmaxf(acc[j][0]+b.x,0.f); buf[r][c0+1]=fmaxf(acc[j][1]+b.y,0.f); buf[r][c0+2]=fmaxf(acc[j][2]+b.z,0.f); buf[r][c0+3]=fmaxf(acc[j][3]+b.w,0.f);} }
    f_gemm(aT, wt, acc, row0, nullptr,0,nullptr,&buf[0][0],FBUFP,200, chh+600,800,nullptr,0,200, p2w,400,400,nullptr,0, DDIM, tid,tr,tc);
    if (c0 < DDIM) { const float4 b = *(const float4*)&p2b[c0];
        #pragma unroll
        for (int j=0;j<8;++j){int r=tr*8+j; buf[r][c0]=fmaxf(acc[j][0]+b.x,0.f); buf[r][c0+1]=fmaxf(acc[j][1]+b.y,0.f); buf[r][c0+2]=fmaxf(acc[j][2]+b.z,0.f); buf[r][c0+3]=fmaxf(acc[j][3]+b.w,0.f);} }
    f_gemm(aT, wt, acc, row0, emb, DDIM, tok, nullptr,0,200, nullptr,0,nullptr,0,0, fxw,200,200,nullptr,0, DDIM, tid,tr,tc);
    float fxr[8][4];
    { float4 b = make_float4(0,0,0,0); if (c0<DDIM) b = *(const float4*)&fxb[c0];
      #pragma unroll
      for (int j=0;j<8;++j){fxr[j][0]=acc[j][0]+b.x;fxr[j][1]=acc[j][1]+b.y;fxr[j][2]=acc[j][2]+b.z;fxr[j][3]=acc[j][3]+b.w;} }
    float csum[8][4];
    #pragma unroll
    for (int j=0;j<8;++j)
        #pragma unroll
        for (int i=0;i<4;++i) csum[j][i]=0.f;
    for (int cc_=0; cc_<4; ++cc_) {
        f_gemm(aT, wt, acc, row0, chh+cc_*200,800,nullptr,nullptr,0,200, nullptr,0,nullptr,0,0, fhw,200,200,nullptr,0, DDIM, tid,tr,tc);
        if (c0 < DDIM) { const float4 b = *(const float4*)&fhb[c0];
            #pragma unroll
            for (int j=0;j<8;++j){ const long r=row0+tr*8+j; const float4 cv=*(const float4*)&chc[r*800+cc_*200+c0];
                csum[j][0]+=sgm_f(acc[j][0]+b.x+fxr[j][0])*cv.x; csum[j][1]+=sgm_f(acc[j][1]+b.y+fxr[j][1])*cv.y;
                csum[j][2]+=sgm_f(acc[j][2]+b.z+fxr[j][2])*cv.z; csum[j][3]+=sgm_f(acc[j][3]+b.w+fxr[j][3])*cv.w; } }
    }
    f_gemm(aT, wt, acc, row0, emb, DDIM, tok, nullptr,0,200, nullptr,0,&buf[0][0],FBUFP,200, ixw,200,200,ihw,200, DDIM, tid,tr,tc);
    float gi[8][4];
    { float4 b1=make_float4(0,0,0,0),b2=b1; if(c0<DDIM){b1=*(const float4*)&ixb[c0];b2=*(const float4*)&ihb[c0];}
      #pragma unroll
      for(int j=0;j<8;++j){gi[j][0]=sgm_f(acc[j][0]+b1.x+b2.x);gi[j][1]=sgm_f(acc[j][1]+b1.y+b2.y);gi[j][2]=sgm_f(acc[j][2]+b1.z+b2.z);gi[j][3]=sgm_f(acc[j][3]+b1.w+b2.w);} }
    f_gemm(aT, wt, acc, row0, emb, DDIM, tok, nullptr,0,200, nullptr,0,&buf[0][0],FBUFP,200, uxw,200,200,uhw,200, DDIM, tid,tr,tc);
    float cval[8][4];
    { float4 b1=make_float4(0,0,0,0),b2=b1; if(c0<DDIM){b1=*(const float4*)&uxb[c0];b2=*(const float4*)&uhb[c0];}
      #pragma unroll
      for(int j=0;j<8;++j){cval[j][0]=gi[j][0]*tanhf(acc[j][0]+b1.x+b2.x)+csum[j][0];cval[j][1]=gi[j][1]*tanhf(acc[j][1]+b1.y+b2.y)+csum[j][1];
                           cval[j][2]=gi[j][2]*tanhf(acc[j][2]+b1.z+b2.z)+csum[j][2];cval[j][3]=gi[j][3]*tanhf(acc[j][3]+b1.w+b2.w)+csum[j][3];} }
    f_gemm(aT, wt, acc, row0, emb, DDIM, tok, nullptr,0,200, nullptr,0,&buf[0][0],FBUFP,200, oxw,200,200,ohw,200, DDIM, tid,tr,tc);
    if (c0 < DDIM) { const float4 b1=*(const float4*)&oxb[c0], b2=*(const float4*)&ohb[c0];
        #pragma unroll
        for(int j=0;j<8;++j){int r=tr*8+j;
            buf[r][c0]=sgm_f(acc[j][0]+b1.x+b2.x)*tanhf(cval[j][0]); buf[r][c0+1]=sgm_f(acc[j][1]+b1.y+b2.y)*tanhf(cval[j][1]);
            buf[r][c0+2]=sgm_f(acc[j][2]+b1.z+b2.z)*tanhf(cval[j][2]); buf[r][c0+3]=sgm_f(acc[j][3]+b1.w+b2.w)*tanhf(cval[j][3]);} }
    f_gemm(aT, wt, acc, row0, nullptr,0,nullptr,&buf[0][0],FBUFP,200, nullptr,0,nullptr,0,0, fc2w,200,200,nullptr,0, NCLS, tid,tr,tc);
    #pragma unroll
    for (int j=0;j<8;++j){ const long r=row0+tr*8+j;
        #pragma unroll
        for (int i=0;i<4;++i){ const int col=c0+i; if (col<NCLS) out[r*NCLS+col]=acc[j][i]+fc2b[col]; } }
}

// ================= launch =================
extern "C" void kernel_launch(void* const* d_in, const int* in_sizes, int n_in,
                              void* d_out, int out_size, void* d_ws, size_t ws_size,
                              hipStream_t stream)
{
    const int*   tok  = (const int*)  d_in[0];
    const float* chc  = (const float*)d_in[1];
    const float* chh  = (const float*)d_in[2];
    const float* emb  = (const float*)d_in[3];
    const float* p1w  = (const float*)d_in[4];
    const float* p1b  = (const float*)d_in[5];
    const float* p2w  = (const float*)d_in[6];
    const float* p2b  = (const float*)d_in[7];
    const float* ixw  = (const float*)d_in[8];
    const float* ixb  = (const float*)d_in[9];
    const float* ihw  = (const float*)d_in[10];
    const float* ihb  = (const float*)d_in[11];
    const float* fxw  = (const float*)d_in[12];
    const float* fxb  = (const float*)d_in[13];
    const float* fhw  = (const float*)d_in[14];
    const float* fhb  = (const float*)d_in[15];
    const float* uxw  = (const float*)d_in[16];
    const float* uxb  = (const float*)d_in[17];
    const float* uhw  = (const float*)d_in[18];
    const float* uhb  = (const float*)d_in[19];
    const float* oxw  = (const float*)d_in[20];
    const float* oxb  = (const float*)d_in[21];
    const float* ohw  = (const float*)d_in[22];
    const float* ohb  = (const float*)d_in[23];
    const float* fc2w = (const float*)d_in[24];
    const float* fc2b = (const float*)d_in[25];
    float* out = (float*)d_out;

    if (ws_size >= W_TOTAL_BYTES) {
        short* ws = (short*)d_ws;
        hipLaunchKernelGGL(wprep, dim3((W_TOTAL_ELEMS + 255) / 256), dim3(256), 0, stream,
                           p1w, p2w, fxw, fhw, ixw, ihw, uxw, uhw, oxw, ohw, fc2w, ws);
        hipLaunchKernelGGL(fused_v7, dim3(NNODES / R), dim3(256), 0, stream,
                           tok, chc, chh, emb,
                           p1b, p2b, ixb, ihb, fxb, fhb, uxb, uhb, oxb, ohb, fc2b,
                           ws, out);
    } else {
        hipLaunchKernelGGL(fused_fp32, dim3(NNODES / FRT), dim3(256), 0, stream,
                           tok, chc, chh, emb, p1w, p1b, p2w, p2b,
                           ixw, ixb, ihw, ihb, fxw, fxb, fhw, fhb,
                           uxw, uxb, uhw, uhb, oxw, oxb, ohw, ohb, fc2w, fc2b, out);
    }
}